// Round 1
// baseline (714.338 us; speedup 1.0000x reference)
//
#include <hip/hip_runtime.h>

// Quantized vector-matrix multiply: out[n] = sum_k (x[k]-Xzp)*Xs * (y[k,n]-Yzp)*Ys
// Exact-integer reformulation:
//   out[n] = Xs*Ys * ( sum_k xs[k]*y[k,n] - Yzp*sum_k xs[k] ),  xs = x - X_ZP
// Max |acc| ~ 8192*152*127 ~ 1.6e8 -> fits int32 exactly.
//
// R5->R6: CONTIGUOUS-CHUNK split-K. R5 read y in 4 KiB stripes with a 64 KiB
// stride (16 column-blocks x 128 k-chunks) and sustained only ~1.8 TB/s. Now
// each of 512 blocks owns 16 FULL consecutive rows = a private 1 MiB contiguous
// span, streamed memcpy-style (m13 pattern: 6.29 TB/s). Per-thread 16x ivec4
// register accumulators over the full row width. Start phase is staggered per
// block at both 64 KiB (row) and 4 KiB (j-stripe) granularity with coprime
// multipliers (exact: sum is order-independent) so concurrent blocks cover all
// HBM interleave units instead of advancing in lockstep.
// Reduce is two-stage so it isn't per-CU-BW-bound (256 blocks then 16).

constexpr int K = 8192;
constexpr int N = 16384;
constexpr float X_SCALE = 0.0215f;
constexpr int   X_ZP    = -25;
constexpr float Y_SCALE = 0.0176f;
constexpr int   Y_ZP    = 18;

constexpr int BLOCK   = 256;
constexpr int N4      = N / 4;              // 4096 ivec4 per row
constexpr int SPLIT_K = 512;                // blocks; 2/CU via launch_bounds
constexpr int KCHUNK  = K / SPLIT_K;        // 16 rows per block (1 MiB chunk)
constexpr int JVEC    = N4 / BLOCK;         // 16 ivec4 per thread per row
constexpr int RED1      = 16;               // stage-1 reduction groups
constexpr int RED1_SPAN = SPLIT_K / RED1;   // 32 chunks summed per stage-1 block

typedef int ivec4 __attribute__((ext_vector_type(4)));

__global__ __launch_bounds__(BLOCK, 2) void qgemv_partial(const int* __restrict__ x,
                                                          const ivec4* __restrict__ y,
                                                          ivec4* __restrict__ ws) {
    __shared__ int xs[KCHUNK];
    const int kc = blockIdx.x;
    const int k0 = kc * KCHUNK;

    // Stage x chunk into LDS, pre-shifted by zero point (broadcast reads).
    if (threadIdx.x < KCHUNK)
        xs[threadIdx.x] = x[k0 + threadIdx.x] - X_ZP;
    __syncthreads();

    // Phase stagger (order-independent sum): decorrelate concurrent blocks'
    // instantaneous HBM footprint at 64 KiB (row) AND 4 KiB (stripe) scales.
    // Multipliers 7 and 5 are coprime to 16 so adjacent blocks get distinct,
    // decoupled phases.
    const int r0 = (kc * 7) & (KCHUNK - 1);
    const int j0 = (kc * 5) & (JVEC - 1);

    // acc[jj] accumulates column stripe j = (j0+jj)&15 -- compile-time index
    // into the register array, runtime-uniform stripe mapping (no scratch).
    ivec4 acc[JVEC];
#pragma unroll
    for (int j = 0; j < JVEC; ++j) {
        acc[j].x = 0; acc[j].y = 0; acc[j].z = 0; acc[j].w = 0;
    }
    int sx = 0;

#pragma unroll 1
    for (int rr = 0; rr < KCHUNK; ++rr) {
        const int r = (r0 + rr) & (KCHUNK - 1);
        const int a = xs[r];
        sx += a;
        const ivec4* __restrict__ yp = y + (size_t)(k0 + r) * N4 + threadIdx.x;
#pragma unroll
        for (int jj = 0; jj < JVEC; ++jj) {
            const int j = (j0 + jj) & (JVEC - 1);
            const ivec4 v = __builtin_nontemporal_load(&yp[j * BLOCK]);
            acc[jj].x += a * v.x;
            acc[jj].y += a * v.y;
            acc[jj].z += a * v.z;
            acc[jj].w += a * v.w;
        }
    }

    // Fold this chunk's zero-point correction into the partial -> reduce is a pure sum.
    const int corr = Y_ZP * sx;
    ivec4* __restrict__ wp = ws + (size_t)kc * N4 + threadIdx.x;
#pragma unroll
    for (int jj = 0; jj < JVEC; ++jj) {
        const int j = (j0 + jj) & (JVEC - 1);
        ivec4 p = acc[jj];
        p.x -= corr; p.y -= corr; p.z -= corr; p.w -= corr;
        wp[j * BLOCK] = p;
    }
}

// Stage 1: 256 blocks, each sums RED1_SPAN chunks for a 256-wide col4 tile.
__global__ __launch_bounds__(BLOCK) void qgemv_reduce1(const ivec4* __restrict__ ws,
                                                       ivec4* __restrict__ ws2) {
    const int cb = blockIdx.x & (N4 / BLOCK - 1);   // 16 column tiles
    const int kb = blockIdx.x / (N4 / BLOCK);       // 16 k groups
    const int col4 = cb * BLOCK + threadIdx.x;
    const int kc0 = kb * RED1_SPAN;
    int sx = 0, sy = 0, sz = 0, sw = 0;
#pragma unroll 8
    for (int i = 0; i < RED1_SPAN; ++i) {
        ivec4 v = ws[(size_t)(kc0 + i) * N4 + col4];
        sx += v.x; sy += v.y; sz += v.z; sw += v.w;
    }
    ivec4 p;
    p.x = sx; p.y = sy; p.z = sz; p.w = sw;
    ws2[(size_t)kb * N4 + col4] = p;
}

// Stage 2: 16 blocks, sum the 16 stage-1 partials, scale, emit fp32.
__global__ __launch_bounds__(BLOCK) void qgemv_reduce2(const ivec4* __restrict__ ws2,
                                                       float* __restrict__ out) {
    const int col4 = blockIdx.x * BLOCK + threadIdx.x;
    int sx = 0, sy = 0, sz = 0, sw = 0;
#pragma unroll
    for (int kb = 0; kb < RED1; ++kb) {
        ivec4 v = ws2[(size_t)kb * N4 + col4];
        sx += v.x; sy += v.y; sz += v.z; sw += v.w;
    }
    const float s = X_SCALE * Y_SCALE;
    float4 o;
    o.x = s * (float)sx;
    o.y = s * (float)sy;
    o.z = s * (float)sz;
    o.w = s * (float)sw;
    ((float4*)out)[col4] = o;
}

extern "C" void kernel_launch(void* const* d_in, const int* in_sizes, int n_in,
                              void* d_out, int out_size, void* d_ws, size_t ws_size,
                              hipStream_t stream) {
    const int* x = (const int*)d_in[0];
    const ivec4* y = (const ivec4*)d_in[1];
    float* out = (float*)d_out;
    ivec4* ws = (ivec4*)d_ws;                        // 512 x 4096 x 16 B = 32 MiB
    ivec4* ws2 = ws + (size_t)SPLIT_K * N4;          // + 16 x 4096 x 16 B = 1 MiB

    qgemv_partial<<<SPLIT_K, BLOCK, 0, stream>>>(x, y, ws);
    qgemv_reduce1<<<(N4 / BLOCK) * RED1, BLOCK, 0, stream>>>(ws, ws2);
    qgemv_reduce2<<<N4 / BLOCK, BLOCK, 0, stream>>>(ws2, out);
}

// Round 2
// 677.187 us; speedup vs baseline: 1.0549x; 1.0549x over previous
//
#include <hip/hip_runtime.h>

// Quantized vector-matrix multiply: out[n] = sum_k (x[k]-Xzp)*Xs * (y[k,n]-Yzp)*Ys
// Exact-integer reformulation:
//   out[n] = Xs*Ys * ( sum_k xs[k]*y[k,n] - Yzp*sum_k xs[k] ),  xs = x - X_ZP
// Max |acc| ~ 8192*152*127 ~ 1.6e8 -> fits int32 exactly.
//
// R6->R7: GRID-SWEEP k interleave (memcpy-clone address stream). R5 (4 KiB
// stripes, 64-consecutive-row chunks, phase rotation) ran ~1.8 TB/s; R6
// (1 MiB private chunks, 2 blocks/CU) was worse. The measured-6.29-TB/s copy
// pattern (m13) is: flat index f = b*256+t, step = grid*256 -- the whole grid
// reads ONE contiguous 8 MiB window per iteration, sweeping memory in order.
// This kernel reproduces that stream exactly: block b owns k-class kb = b/16
// (uniform), column stripe (b%16)*256+t, and iterates rows kb + 128*i,
// i = 0..63. Per-thread stride is 8 MiB; the grid's instantaneous footprint is
// rows [128i, 128i+128) x all columns = contiguous 8 MiB. Full occupancy
// (8 blocks/CU, 32 waves/CU), all 2048 blocks co-resident, lockstep desired.
// Partials (zero-point folded, exact) -> 128 x 4096 ivec4 = 8 MiB ws.
// Reduce: single launch, 128 blocks (32 col4 x 8 k-groups, LDS combine).

constexpr int K = 8192;
constexpr int N = 16384;
constexpr float X_SCALE = 0.0215f;
constexpr int   X_ZP    = -25;
constexpr float Y_SCALE = 0.0176f;
constexpr int   Y_ZP    = 18;

constexpr int BLOCK  = 256;
constexpr int N4     = N / 4;               // 4096 ivec4 per row
constexpr int NBLK_N = 16;                  // column stripes (256 ivec4 each)
constexpr int SPLIT_K = 128;                // k-classes; grid = 128*16 = 2048
constexpr int KITER  = K / SPLIT_K;         // 64 rows per class, stride 128

typedef int ivec4 __attribute__((ext_vector_type(4)));

__global__ __launch_bounds__(BLOCK, 8) void qgemv_partial(const int* __restrict__ x,
                                                          const ivec4* __restrict__ y,
                                                          ivec4* __restrict__ ws) {
    __shared__ int xs[KITER];

    const int nb = blockIdx.x % NBLK_N;     // column stripe
    const int kb = blockIdx.x / NBLK_N;     // k-class (block-uniform)

    // Stage this class's 64 x values (stride-128 gather), pre-shifted by zero point.
    if (threadIdx.x < KITER)
        xs[threadIdx.x] = x[kb + SPLIT_K * threadIdx.x] - X_ZP;
    __syncthreads();

    const int col4 = nb * (BLOCK) + threadIdx.x;          // vec4 column index
    const ivec4* __restrict__ yv = y + (size_t)kb * N4 + col4;

    int acc0 = 0, acc1 = 0, acc2 = 0, acc3 = 0;
    int sx = 0;

#pragma unroll 8
    for (int i = 0; i < KITER; ++i) {
        // row = kb + 128*i  ->  flat stride per iteration = 8 MiB (grid sweep)
        ivec4 v = __builtin_nontemporal_load(&yv[(size_t)i * (SPLIT_K * N4)]);
        int a = xs[i];
        sx   += a;
        acc0 += a * v.x;
        acc1 += a * v.y;
        acc2 += a * v.z;
        acc3 += a * v.w;
    }

    // Fold this class's zero-point correction into the partial -> reduce is a pure sum.
    const int corr = Y_ZP * sx;
    ivec4 p;
    p.x = acc0 - corr;
    p.y = acc1 - corr;
    p.z = acc2 - corr;
    p.w = acc3 - corr;
    ws[(size_t)kb * N4 + col4] = p;
}

// Single-launch reduce over 128 partials per col4.
// 128 blocks; each handles 32 col4. Threads: c = tid%32 (col4), g = tid/32
// (8 k-groups of 16 partials). LDS-combine the 8 group sums, scale, emit fp32.
constexpr int RBLK = 128;
constexpr int CPB  = N4 / RBLK;             // 32 col4 per block
constexpr int GRP  = BLOCK / CPB;           // 8 k-groups
constexpr int PER  = SPLIT_K / GRP;         // 16 partials per thread

__global__ __launch_bounds__(BLOCK) void qgemv_reduce(const ivec4* __restrict__ ws,
                                                      float* __restrict__ out) {
    __shared__ ivec4 red[GRP][CPB];         // 4 KiB
    const int c = threadIdx.x % CPB;
    const int g = threadIdx.x / CPB;
    const int col4 = blockIdx.x * CPB + c;

    int sx = 0, sy = 0, sz = 0, sw = 0;
#pragma unroll
    for (int i = 0; i < PER; ++i) {
        ivec4 v = ws[(size_t)(g * PER + i) * N4 + col4];
        sx += v.x; sy += v.y; sz += v.z; sw += v.w;
    }
    ivec4 p; p.x = sx; p.y = sy; p.z = sz; p.w = sw;
    red[g][c] = p;
    __syncthreads();

    if (g == 0) {
        ivec4 t = red[0][c];
#pragma unroll
        for (int gg = 1; gg < GRP; ++gg) {
            ivec4 v = red[gg][c];
            t.x += v.x; t.y += v.y; t.z += v.z; t.w += v.w;
        }
        const float s = X_SCALE * Y_SCALE;
        float4 o;
        o.x = s * (float)t.x;
        o.y = s * (float)t.y;
        o.z = s * (float)t.z;
        o.w = s * (float)t.w;
        ((float4*)out)[col4] = o;
    }
}

extern "C" void kernel_launch(void* const* d_in, const int* in_sizes, int n_in,
                              void* d_out, int out_size, void* d_ws, size_t ws_size,
                              hipStream_t stream) {
    const int* x = (const int*)d_in[0];
    const ivec4* y = (const ivec4*)d_in[1];
    float* out = (float*)d_out;
    ivec4* ws = (ivec4*)d_ws;               // 128 x 4096 x 16 B = 8 MiB of workspace

    qgemv_partial<<<SPLIT_K * NBLK_N, BLOCK, 0, stream>>>(x, y, ws);
    qgemv_reduce<<<RBLK, BLOCK, 0, stream>>>(ws, out);
}

// Round 3
// 673.293 us; speedup vs baseline: 1.0610x; 1.0058x over previous
//
#include <hip/hip_runtime.h>

// Quantized vector-matrix multiply: out[n] = sum_k (x[k]-Xzp)*Xs * (y[k,n]-Yzp)*Ys
// Exact-integer reformulation:
//   out[n] = Xs*Ys * ( sum_k xs[k]*y[k,n] - Yzp*sum_k xs[k] ),  xs = x - X_ZP
// Max |acc| ~ 8192*152*127 ~ 1.6e8 -> fits int32 exactly.
//
// R7->R8: DROP NONTEMPORAL LOADS. Every variant across both sessions (4 KiB
// stripe walk ~1.8 TB/s, 1 MiB private chunks, memcpy-clone grid sweep) used
// __builtin_nontemporal_load and all were pattern/occupancy-insensitive at
// ~2-3 TB/s -- the signature of a per-access-type cap, not scheduling. Plain
// cached reads restore the normal TCC line path (the 6.4 TB/s fills and the
// m13 6.29 TB/s copy both use the cached path). Structure is otherwise R5's
// best-measured kernel (4 KiB stripes, 64-row chunks, phase rotation, 8
// blocks/CU) + R7's verified wide reduce (128 blocks, LDS combine).

constexpr int K = 8192;
constexpr int N = 16384;
constexpr float X_SCALE = 0.0215f;
constexpr int   X_ZP    = -25;
constexpr float Y_SCALE = 0.0176f;
constexpr int   Y_ZP    = 18;

constexpr int BLOCK = 256;
constexpr int VEC   = 4;                       // 16 B/lane loads
constexpr int COLS_PER_BLOCK = BLOCK * VEC;    // 1024
constexpr int NBLK_N = N / COLS_PER_BLOCK;     // 16
constexpr int SPLIT_K = 128;                   // 2048 blocks -> 8 blocks/CU, 32 waves/CU
constexpr int KCHUNK = K / SPLIT_K;            // 64
constexpr int N4 = N / 4;                      // vec4 elements per row

typedef int ivec4 __attribute__((ext_vector_type(4)));

__global__ __launch_bounds__(BLOCK, 8) void qgemv_partial(const int* __restrict__ x,
                                                          const ivec4* __restrict__ y,
                                                          ivec4* __restrict__ ws) {
    __shared__ int xs[KCHUNK];

    const int nb = blockIdx.x % NBLK_N;
    const int kc = blockIdx.x / NBLK_N;
    const int k0 = kc * KCHUNK;

    // Stage x chunk into LDS, pre-shifted by zero point (broadcast reads: conflict-free).
    if (threadIdx.x < KCHUNK)
        xs[threadIdx.x] = x[k0 + threadIdx.x] - X_ZP;
    __syncthreads();

    const int col4 = nb * (COLS_PER_BLOCK / 4) + threadIdx.x;  // vec4 column index
    const ivec4* __restrict__ yv = y + (size_t)k0 * N4 + col4;

    // Per-block rotation phase: spread mod 8 AND mod 64 so concurrent blocks hit
    // disjoint interleave units.
    const int r0 = (13 * kc + 7 * nb) & (KCHUNK - 1);

    int acc0 = 0, acc1 = 0, acc2 = 0, acc3 = 0;
    int sx = 0;

#pragma unroll 8
    for (int i = 0; i < KCHUNK; ++i) {
        int k = r0 + i;
        if (k >= KCHUNK) k -= KCHUNK;
        ivec4 v = yv[(size_t)k * N4];          // PLAIN cached load (the A/B)
        int a = xs[k];
        sx   += a;
        acc0 += a * v.x;
        acc1 += a * v.y;
        acc2 += a * v.z;
        acc3 += a * v.w;
    }

    // Fold this chunk's zero-point correction into the partial -> reduce is a pure sum.
    const int corr = Y_ZP * sx;
    ivec4 p;
    p.x = acc0 - corr;
    p.y = acc1 - corr;
    p.z = acc2 - corr;
    p.w = acc3 - corr;
    ws[(size_t)kc * N4 + col4] = p;
}

// Single-launch reduce over 128 partials per col4 (verified in R7).
// 128 blocks; each handles 32 col4. Threads: c = tid%32 (col4), g = tid/32
// (8 k-groups of 16 partials). LDS-combine the 8 group sums, scale, emit fp32.
constexpr int RBLK = 128;
constexpr int CPB  = N4 / RBLK;             // 32 col4 per block
constexpr int GRP  = BLOCK / CPB;           // 8 k-groups
constexpr int PER  = SPLIT_K / GRP;         // 16 partials per thread

__global__ __launch_bounds__(BLOCK) void qgemv_reduce(const ivec4* __restrict__ ws,
                                                      float* __restrict__ out) {
    __shared__ ivec4 red[GRP][CPB];         // 4 KiB
    const int c = threadIdx.x % CPB;
    const int g = threadIdx.x / CPB;
    const int col4 = blockIdx.x * CPB + c;

    int sx = 0, sy = 0, sz = 0, sw = 0;
#pragma unroll
    for (int i = 0; i < PER; ++i) {
        ivec4 v = ws[(size_t)(g * PER + i) * N4 + col4];
        sx += v.x; sy += v.y; sz += v.z; sw += v.w;
    }
    ivec4 p; p.x = sx; p.y = sy; p.z = sz; p.w = sw;
    red[g][c] = p;
    __syncthreads();

    if (g == 0) {
        ivec4 t = red[0][c];
#pragma unroll
        for (int gg = 1; gg < GRP; ++gg) {
            ivec4 v = red[gg][c];
            t.x += v.x; t.y += v.y; t.z += v.z; t.w += v.w;
        }
        const float s = X_SCALE * Y_SCALE;
        float4 o;
        o.x = s * (float)t.x;
        o.y = s * (float)t.y;
        o.z = s * (float)t.z;
        o.w = s * (float)t.w;
        ((float4*)out)[col4] = o;
    }
}

extern "C" void kernel_launch(void* const* d_in, const int* in_sizes, int n_in,
                              void* d_out, int out_size, void* d_ws, size_t ws_size,
                              hipStream_t stream) {
    const int* x = (const int*)d_in[0];
    const ivec4* y = (const ivec4*)d_in[1];
    float* out = (float*)d_out;
    ivec4* ws = (ivec4*)d_ws;   // 128 x 4096 x 16 B = 8 MiB of the workspace

    qgemv_partial<<<SPLIT_K * NBLK_N, BLOCK, 0, stream>>>(x, y, ws);
    qgemv_reduce<<<RBLK, BLOCK, 0, stream>>>(ws, out);
}